// Round 10
// baseline (347.745 us; speedup 1.0000x reference)
//
#include <hip/hip_runtime.h>
#include <hip/hip_bf16.h>

#define MD 8192
#define KD 4096
#define ND 4096

typedef __bf16 bf16x8 __attribute__((ext_vector_type(8)));
typedef float f32x4 __attribute__((ext_vector_type(4)));

__device__ __forceinline__ float gelu_ss(float v) {
    float t = 0.7978845608f * fmaf(0.044715f * v * v, v, v);
    float r = t * __builtin_amdgcn_rcpf(1.0f + fabsf(t));
    return 0.5f * v * (1.0f + r);
}

// ---------------------------------------------------------------------------
// fp32 -> bf16 convert (memory-bound; inputs are L3-resident after 1st replay)
// ---------------------------------------------------------------------------
__global__ void cvt_bf16(const float* __restrict__ in, __bf16* __restrict__ out, int n8) {
    int i = blockIdx.x * 256 + threadIdx.x;
    int stride = gridDim.x * 256;
    for (; i < n8; i += stride) {
        const float4* p = (const float4*)(in + (size_t)i * 8);
        float4 a = p[0], b = p[1];
        bf16x8 v;
        v[0]=(__bf16)a.x; v[1]=(__bf16)a.y; v[2]=(__bf16)a.z; v[3]=(__bf16)a.w;
        v[4]=(__bf16)b.x; v[5]=(__bf16)b.y; v[6]=(__bf16)b.z; v[7]=(__bf16)b.w;
        *(bf16x8*)(out + (size_t)i * 8) = v;
    }
}

// ---------------------------------------------------------------------------
// GEMM+epilogue, round 10: 128x256 tile, 8 waves (64x64 each, acc=64 VGPR),
// BK=32, TRIPLE-buffered LDS (72 KiB) -> 2 blocks/CU (launch_bounds 512,4).
// Simple never-drain loop: vmcnt(3) + 1 barrier + 8 ds_reads + 3-load stage
// (lead 2) + lgkm(0) + 16 MFMA per K-tile. Cross-block TLP hides the drains.
// ---------------------------------------------------------------------------
#define BMg 128
#define BNg 256
#define BKg 32
#define KTg (KD / BKg)                    // 128
#define NBLKg ((MD / BMg) * (ND / BNg))   // 64*16 = 1024

__device__ __forceinline__ void gload_lds16(const void* g, void* l) {
    __builtin_amdgcn_global_load_lds(
        (const __attribute__((address_space(1))) void*)g,
        (__attribute__((address_space(3))) void*)l, 16, 0, 0);
}

__global__ __launch_bounds__(512, 4) void gemm_bf16_lse(
    const __bf16* __restrict__ xb, const __bf16* __restrict__ Wb,
    const float* __restrict__ bias, float* __restrict__ rowsum)
{
    // 3 bufs x [A:128 rows | B:256 rows] x 32 cols bf16 = 3 x 24 KiB = 72 KiB
    __shared__ alignas(16) __bf16 lds[3][(BMg + BNg) * BKg];

    unsigned bid  = blockIdx.x;
    unsigned sbid = (bid & 7u) * (NBLKg / 8u) + (bid >> 3);   // bijective, 1024%8==0
    unsigned bm = sbid / (ND / BNg);     // 0..63
    unsigned bn = sbid % (ND / BNg);     // 0..15

    const unsigned tid  = threadIdx.x;
    const unsigned lane = tid & 63u;
    const unsigned wid  = tid >> 6;      // 0..7
    const unsigned wr   = wid >> 2;      // 0..1 -> 64-row halves of A
    const unsigned wc   = wid & 3u;      // 0..3 -> 64-col quarters of B
    const unsigned lr   = lane & 15u;
    const unsigned kg   = lane >> 4;

    // staging: 1536 chunks of 16B; chunk c -> LDS row c>>2 (A:0-127, B:128-383),
    // slot c&3. LDS linear (DMA dest = uniform base + lane*16); global col-slot
    // pre-swizzled cg = slot ^ ((ldsrow>>1)&3)  (rule #21; 0-conflict, r3).
    unsigned c0 = tid, c1 = tid + 512u, c2 = tid + 1024u;
    unsigned r0 = c0 >> 2, g0 = (c0 & 3u) ^ ((r0 >> 1) & 3u);
    unsigned r1 = c1 >> 2, g1 = (c1 & 3u) ^ ((r1 >> 1) & 3u);
    unsigned r2 = c2 >> 2, g2 = (c2 & 3u) ^ ((r2 >> 1) & 3u);
    const __bf16* pA  = xb + (size_t)(bm * BMg + r0) * KD + g0 * 8u;
    const __bf16* pB0 = Wb + (size_t)(bn * BNg + (r1 - 128u)) * KD + g1 * 8u;
    const __bf16* pB1 = Wb + (size_t)(bn * BNg + (r2 - 128u)) * KD + g2 * 8u;

    f32x4 acc[4][4] = {};

    auto stage = [&](unsigned bsel, int t) {
        gload_lds16(pA  + (size_t)t * 32u, &lds[bsel][c0 * 8u]);
        gload_lds16(pB0 + (size_t)t * 32u, &lds[bsel][c1 * 8u]);
        gload_lds16(pB1 + (size_t)t * 32u, &lds[bsel][c2 * 8u]);
    };
    // fragment reads: row stride 64B, 16B slot kg swizzled by (ldsrow>>1)&3
    auto loadA = [&](unsigned bsel, bf16x8* dst) {
        const char* As = (const char*)&lds[bsel][0];
        #pragma unroll
        for (int mf = 0; mf < 4; ++mf) {
            unsigned ro = wr * 64u + mf * 16u + lr;
            dst[mf] = *(const bf16x8*)(As + ro * 64u + ((kg ^ ((ro >> 1) & 3u)) * 16u));
        }
    };
    auto loadB = [&](unsigned bsel, bf16x8* dst) {
        const char* Bs = (const char*)&lds[bsel][0];
        #pragma unroll
        for (int nf = 0; nf < 4; ++nf) {
            unsigned ro = 128u + wc * 64u + nf * 16u + lr;
            dst[nf] = *(const bf16x8*)(Bs + ro * 64u + ((kg ^ ((ro >> 1) & 3u)) * 16u));
        }
    };

    // one K-tile: counted vmcnt, barrier, reads, lead-2 stage, lgkm0, 16 MFMA
    auto body = [&](int t, unsigned b, unsigned bs) {
        if (t < KTg - 1) asm volatile("s_waitcnt vmcnt(3)" ::: "memory");
        else             asm volatile("s_waitcnt vmcnt(0)" ::: "memory");
        __builtin_amdgcn_s_barrier();
        bf16x8 aF[4], bF[4];
        loadA(b, aF);
        loadB(b, bF);
        if (t + 2 < KTg) stage(bs, t + 2);
        asm volatile("s_waitcnt lgkmcnt(0)" ::: "memory");
        __builtin_amdgcn_sched_barrier(0);           // rule #18 fence
        #pragma unroll
        for (int mf = 0; mf < 4; ++mf)
            #pragma unroll
            for (int nf = 0; nf < 4; ++nf)
                acc[mf][nf] = __builtin_amdgcn_mfma_f32_16x16x32_bf16(
                    aF[mf], bF[nf], acc[mf][nf], 0, 0, 0);
    };

    // prologue: stage tiles 0,1 (6 loads in flight; vmcnt(3) in iter 0
    // certifies tile 0, leaves tile 1's loads flying)
    stage(0, 0);
    stage(1, 1);

    for (int tt = 0; tt < KTg - 2; tt += 3) {        // 0..125 (42 iters)
        body(tt,     0u, 2u);
        body(tt + 1, 1u, 0u);
        body(tt + 2, 2u, 1u);
    }
    body(KTg - 2, 0u, 2u);                           // t=126 (buf 0)
    body(KTg - 1, 1u, 0u);                           // t=127 (buf 1)

    // ---- epilogue: bias + leaky^2 + gelu^2 + exp + row partial sums ----
    // C/D layout: col = lane&15 (=lr), row = kg*4 + j
    unsigned row_base = bm * BMg + wr * 64u;
    unsigned col_base = bn * BNg + wc * 64u;
    float bb[4];
    #pragma unroll
    for (int nf = 0; nf < 4; ++nf) bb[nf] = bias[col_base + nf * 16u + lr];
    #pragma unroll
    for (int mf = 0; mf < 4; ++mf) {
        float s[4] = {0.f, 0.f, 0.f, 0.f};
        #pragma unroll
        for (int nf = 0; nf < 4; ++nf) {
            #pragma unroll
            for (int j = 0; j < 4; ++j) {
                float v = acc[mf][nf][j] + bb[nf];
                v = v > 0.0f ? v : 1e-4f * v;        // two leaky-relus fused
                v = gelu_ss(gelu_ss(v));
                s[j] += __expf(v);
            }
        }
        #pragma unroll
        for (int j = 0; j < 4; ++j) {
            float t = s[j];
            t += __shfl_xor(t, 1);
            t += __shfl_xor(t, 2);
            t += __shfl_xor(t, 4);
            t += __shfl_xor(t, 8);
            if (lr == 0)
                atomicAdd(&rowsum[row_base + mf * 16u + kg * 4u + j], t);
        }
    }
}

// ---------------------------------------------------------------------------
// Fallback (round-2 kernel): fused fp32 staging, used only if ws too small.
// ---------------------------------------------------------------------------
#define BM 256
#define BN 256
#define BK 64
#define NBLK ((MD / BM) * (ND / BN))

__device__ __forceinline__ unsigned swz(unsigned row, unsigned kbyte) {
    return row * (BK * 2u) + (kbyte ^ ((row & 7u) << 4));
}

__global__ __launch_bounds__(512, 1) void fused_gemm_lse(
    const float* __restrict__ x, const float* __restrict__ W,
    const float* __restrict__ bias, float* __restrict__ rowsum)
{
    __shared__ alignas(16) __bf16 lds[2][2][BM * BK];
    unsigned bid  = blockIdx.x;
    unsigned sbid = (bid & 7u) * (NBLK / 8u) + (bid >> 3);
    unsigned bm = sbid / (ND / BN);
    unsigned bn = sbid % (ND / BN);
    const unsigned tid  = threadIdx.x;
    const unsigned lane = tid & 63u;
    const unsigned wid  = tid >> 6;
    const unsigned wr   = wid >> 2;
    const unsigned wc   = wid & 3u;
    const unsigned lr   = lane & 15u;
    const unsigned kg   = lane >> 4;
    const float* gA = x + (size_t)bm * BM * KD;
    const float* gB = W + (size_t)bn * BN * KD;
    const unsigned s_row = tid >> 3;
    const unsigned s_c8  = tid & 7u;
    f32x4 acc[8][4] = {};
    float4 ra[8], rb[8];
    auto issue = [&](const float* g, int kt, float4* r) {
        #pragma unroll
        for (int i = 0; i < 4; ++i) {
            unsigned row = s_row + 64u * i;
            size_t goff = (size_t)row * KD + (size_t)kt * BK + (size_t)s_c8 * 8u;
            r[i * 2]     = *(const float4*)(g + goff);
            r[i * 2 + 1] = *(const float4*)(g + goff + 4);
        }
    };
    auto writeT = [&](char* dst, const float4* r) {
        #pragma unroll
        for (int i = 0; i < 4; ++i) {
            unsigned row = s_row + 64u * i;
            float4 lo = r[i * 2], hi = r[i * 2 + 1];
            bf16x8 v;
            v[0]=(__bf16)lo.x; v[1]=(__bf16)lo.y; v[2]=(__bf16)lo.z; v[3]=(__bf16)lo.w;
            v[4]=(__bf16)hi.x; v[5]=(__bf16)hi.y; v[6]=(__bf16)hi.z; v[7]=(__bf16)hi.w;
            *(bf16x8*)(dst + swz(row, s_c8 * 16u)) = v;
        }
    };
    auto compute = [&](int cur) {
        const char* AsB = (const char*)&lds[cur][0][0];
        const char* BsB = (const char*)&lds[cur][1][0];
        #pragma unroll
        for (int ks = 0; ks < 2; ++ks) {
            unsigned kb = (unsigned)ks * 64u + kg * 16u;
            bf16x8 bfr[4];
            #pragma unroll
            for (int ni = 0; ni < 4; ++ni)
                bfr[ni] = *(const bf16x8*)(BsB + swz(wc * 64u + ni * 16u + lr, kb));
            #pragma unroll
            for (int mh = 0; mh < 2; ++mh) {
                bf16x8 af[4];
                #pragma unroll
                for (int a = 0; a < 4; ++a)
                    af[a] = *(const bf16x8*)(AsB + swz(wr * 128u + mh * 64u + a * 16u + lr, kb));
                #pragma unroll
                for (int a = 0; a < 4; ++a)
                    #pragma unroll
                    for (int ni = 0; ni < 4; ++ni)
                        acc[mh * 4 + a][ni] = __builtin_amdgcn_mfma_f32_16x16x32_bf16(
                            af[a], bfr[ni], acc[mh * 4 + a][ni], 0, 0, 0);
            }
        }
    };
    issue(gA, 0, ra); issue(gB, 0, rb);
    writeT((char*)&lds[0][0][0], ra);
    writeT((char*)&lds[0][1][0], rb);
    __syncthreads();
    int cur = 0;
    for (int kt = 0; kt < KD / BK - 1; ++kt) {
        issue(gA, kt + 1, ra);
        issue(gB, kt + 1, rb);
        compute(cur);
        writeT((char*)&lds[cur ^ 1][0][0], ra);
        writeT((char*)&lds[cur ^ 1][1][0], rb);
        __syncthreads();
        cur ^= 1;
    }
    compute(cur);
    unsigned row_base = bm * BM + wr * 128u;
    unsigned col_base = bn * BN + wc * 64u;
    float bb[4];
    #pragma unroll
    for (int ni = 0; ni < 4; ++ni) bb[ni] = bias[col_base + ni * 16u + lr];
    #pragma unroll
    for (int mi = 0; mi < 8; ++mi) {
        float s[4] = {0.f, 0.f, 0.f, 0.f};
        #pragma unroll
        for (int ni = 0; ni < 4; ++ni) {
            #pragma unroll
            for (int j = 0; j < 4; ++j) {
                float v = acc[mi][ni][j] + bb[ni];
                v = v > 0.0f ? v : 1e-4f * v;
                v = gelu_ss(gelu_ss(v));
                s[j] += __expf(v);
            }
        }
        #pragma unroll
        for (int j = 0; j < 4; ++j) {
            float t = s[j];
            t += __shfl_xor(t, 1);
            t += __shfl_xor(t, 2);
            t += __shfl_xor(t, 4);
            t += __shfl_xor(t, 8);
            if (lr == 0)
                atomicAdd(&rowsum[row_base + mi * 16u + kg * 4u + j], t);
        }
    }
}

__global__ void lse_log(float* __restrict__ out) {
    int i = blockIdx.x * 256 + threadIdx.x;
    if (i < MD) out[i] = logf(out[i]);
}

extern "C" void kernel_launch(void* const* d_in, const int* in_sizes, int n_in,
                              void* d_out, int out_size, void* d_ws, size_t ws_size,
                              hipStream_t stream) {
    (void)in_sizes; (void)n_in; (void)out_size;
    const float* x = (const float*)d_in[0];
    const float* W = (const float*)d_in[1];
    const float* b = (const float*)d_in[2];
    float* out = (float*)d_out;

    hipMemsetAsync(out, 0, (size_t)MD * sizeof(float), stream);

    size_t need = ((size_t)MD * KD + (size_t)ND * KD) * sizeof(__bf16);  // 100.7 MB
    if (ws_size >= need) {
        __bf16* xb = (__bf16*)d_ws;
        __bf16* Wb = xb + (size_t)MD * KD;
        cvt_bf16<<<2048, 256, 0, stream>>>(x, xb, MD * KD / 8);
        cvt_bf16<<<2048, 256, 0, stream>>>(W, Wb, ND * KD / 8);
        gemm_bf16_lse<<<NBLKg, 512, 0, stream>>>(xb, Wb, b, out);
    } else {
        fused_gemm_lse<<<NBLK, 512, 0, stream>>>(x, W, b, out);
    }
    lse_log<<<MD / 256, 256, 0, stream>>>(out);
}